// Round 1
// baseline (50.654 us; speedup 1.0000x reference)
//
#include <hip/hip_runtime.h>

// Problem dims (fixed by the reference)
#define B_ 1024
#define O_ 256
#define I_ 256
#define S_ 20   // num segments; breakpoints/values have S_+1 entries

// ---------------------------------------------------------------------------
// Kernel 1: transpose values[O][I][S+1] -> Vp[I][S][O] as float2 (v_s, v_{s+1})
// so the main kernel's gather is a single coalesced dwordx2 across o-lanes.
// block = (64 o, 4 i), grid = (O/64, I/4). Reads per thread are 21 sequential
// floats; writes are 64 consecutive float2 per (i,s) -> coalesced.
// ---------------------------------------------------------------------------
__global__ __launch_bounds__(256) void build_vp(const float* __restrict__ values,
                                                float2* __restrict__ vp) {
    int o = blockIdx.x * 64 + threadIdx.x;
    int i = blockIdx.y * 4 + threadIdx.y;
    const float* src = values + (o * I_ + i) * (S_ + 1);
    float v[S_ + 1];
#pragma unroll
    for (int s = 0; s <= S_; ++s) v[s] = src[s];
#pragma unroll
    for (int s = 0; s < S_; ++s) {
        vp[(i * S_ + s) * O_ + o] = make_float2(v[s], v[s + 1]);
    }
}

// ---------------------------------------------------------------------------
// Kernel 2: per (b,i) segment search + weights. Faithful to the reference:
// searchsorted(side='right')-1 against the ACTUAL breakpoint bits (grid is
// identical for every (o,i) -- tiled linspace), t = (x-lo)/(hi-lo+1e-8),
// zeroed outside [lo, hi). Outputs:
//   off[b*I+i] = (i*S + k) * O   (float2-element offset into Vp)
//   w[b*I+i]   = (1-t, t)        (or (0,0) if out of range)
// ---------------------------------------------------------------------------
__global__ __launch_bounds__(256) void build_kt(const float* __restrict__ x,
                                                const float* __restrict__ bp,
                                                int* __restrict__ off,
                                                float2* __restrict__ w) {
    int idx = blockIdx.x * 256 + threadIdx.x;  // idx = b*I + i
    if (idx >= B_ * I_) return;
    float xv = x[idx];
    int i = idx & (I_ - 1);

    float bpr[S_ + 1];
#pragma unroll
    for (int s = 0; s <= S_; ++s) bpr[s] = bp[s];  // broadcast loads

    // searchsorted right: (# of bp <= x) - 1, clipped to [0, S-1]
    int k = -1;
#pragma unroll
    for (int s = 0; s <= S_; ++s) k += (bpr[s] <= xv) ? 1 : 0;
    k = min(max(k, 0), S_ - 1);

    float lo = bpr[k];
    float hi = bpr[k + 1];
    float t = (xv - lo) / (hi - lo + 1e-8f);
    bool inb = (xv >= lo) && (xv < hi);
    float w1 = inb ? t : 0.0f;
    float w0 = inb ? (1.0f - t) : 0.0f;

    off[idx] = (i * S_ + k) * O_;
    w[idx] = make_float2(w0, w1);
}

// ---------------------------------------------------------------------------
// Kernel 3: main accumulation. out[b][o] = sum_i w0*Vp[off].x + w1*Vp[off].y
// block = (256 o-lanes, 2 y), each y-half owns 2 batches -> 4 batches/block,
// grid = B/4 = 256 blocks (1/CU, 8 waves/CU). off/w reads are wave-uniform
// (readfirstlane on y) -> s_load; Vp read is one dwordx2/lane, coalesced.
// ---------------------------------------------------------------------------
__global__ __launch_bounds__(512) void kan_main(const int* __restrict__ off,
                                                const float2* __restrict__ w,
                                                const float2* __restrict__ vp,
                                                float* __restrict__ out) {
    int o = threadIdx.x;
    int yu = __builtin_amdgcn_readfirstlane(threadIdx.y);
    int b0 = blockIdx.x * 4 + yu * 2;

    const int*    offA = off + b0 * I_;
    const int*    offB = off + (b0 + 1) * I_;
    const float2* wA   = w + b0 * I_;
    const float2* wB   = w + (b0 + 1) * I_;

    float acc0 = 0.0f, acc1 = 0.0f;
#pragma unroll 4
    for (int i = 0; i < I_; ++i) {
        int eA = offA[i];
        int eB = offB[i];
        float2 wwA = wA[i];
        float2 wwB = wB[i];
        float2 vA = vp[eA + o];
        float2 vB = vp[eB + o];
        acc0 = fmaf(wwA.x, vA.x, acc0);
        acc0 = fmaf(wwA.y, vA.y, acc0);
        acc1 = fmaf(wwB.x, vB.x, acc1);
        acc1 = fmaf(wwB.y, vB.y, acc1);
    }
    out[b0 * O_ + o]       = acc0;
    out[(b0 + 1) * O_ + o] = acc1;
}

extern "C" void kernel_launch(void* const* d_in, const int* in_sizes, int n_in,
                              void* d_out, int out_size, void* d_ws, size_t ws_size,
                              hipStream_t stream) {
    const float* x      = (const float*)d_in[0];  // [B, I]
    const float* bps    = (const float*)d_in[1];  // [O, I, S+1] (uniform grid)
    const float* values = (const float*)d_in[2];  // [O, I, S+1]
    float* out = (float*)d_out;                   // [B, O]

    // Workspace carve-up (all sizes in bytes):
    //   Vp : I*S*O * sizeof(float2) = 10,485,760
    //   off: B*I   * sizeof(int)    =  1,048,576
    //   w  : B*I   * sizeof(float2) =  2,097,152
    char* ws = (char*)d_ws;
    float2* vp  = (float2*)(ws);
    int*    off = (int*)(ws + (size_t)I_ * S_ * O_ * sizeof(float2));
    float2* w   = (float2*)(ws + (size_t)I_ * S_ * O_ * sizeof(float2)
                               + (size_t)B_ * I_ * sizeof(int));

    // 1) transpose values into paired layout
    build_vp<<<dim3(O_ / 64, I_ / 4), dim3(64, 4), 0, stream>>>(values, vp);
    // 2) per-(b,i) segment search + weights
    build_kt<<<dim3((B_ * I_) / 256), dim3(256), 0, stream>>>(x, bps, off, w);
    // 3) main accumulation
    kan_main<<<dim3(B_ / 4), dim3(256, 2), 0, stream>>>(off, w, vp, out);
}